// Round 10
// baseline (52.782 us; speedup 1.0000x reference)
//
#include <hip/hip_runtime.h>

#define B 4
#define L 200
#define N 160
#define HS 768
#define HD 256
#define C 16

#define KP 784             // padded K: 768 data + 1 gate(bias) + 15 zero
#define WJ 48              // fused cols: A(16) | B(16) | T(16)
#define NROW (B * N)       // 640
#define NBLK 160           // grid size; 1 block/CU -> co-residency guaranteed
#define KSL4 196           // KP/4, per-k-slice length in phase 1
#define WCT_STRIDE 260
#define KH 80              // finalize k-half

// ---------------------------------------------------------------------------
// Flag barrier, contention-free: per-block flags, RELAXED polls, single
// release fence before arrive + single acquire fence after wait.
// (R5's 40us/barrier is attributed to per-poll acquire-invalidates + 256-way
// atomicAdd contention; both eliminated here.)
// ---------------------------------------------------------------------------
__device__ __forceinline__ void grid_bar(unsigned* flags, int blk, int t, unsigned phase) {
    __syncthreads();
    if (t == 0) {
        __builtin_amdgcn_fence(__ATOMIC_RELEASE, "agent");   // wb dirty L2 once
        __hip_atomic_store(&flags[blk], phase, __ATOMIC_RELAXED, __HIP_MEMORY_SCOPE_AGENT);
    }
    if (t < NBLK) {
        int guard = 0;
        while (__hip_atomic_load(&flags[t], __ATOMIC_RELAXED, __HIP_MEMORY_SCOPE_AGENT) < phase
               && guard < (1 << 22)) {
            __builtin_amdgcn_s_sleep(4);
            ++guard;
        }
    }
    __builtin_amdgcn_fence(__ATOMIC_ACQUIRE, "agent");       // inv once
    __syncthreads();
}

// ---------------------------------------------------------------------------
// Single persistent kernel, 160 blocks x 256 threads.
//  bar0   : flag self-reset (handles stale 0xAA / 2 without a memset node)
//  phase0 : pool 4 rows -> LDS (never hits global);
//           blocks 0..143 also build one Wfull k-stripe, block 144 bias+zeros
//  bar1   : Wfull visible
//  phase1 : 4-row x 48-col GEMM from LDS hs + global Wfull -> AB/T
//  bar2   : AB/T visible
//  phase2 : per (b, i-tile, k-half) scan + emit (R9 finalize)
// ---------------------------------------------------------------------------
__global__ __launch_bounds__(256) void mega_kernel(
    const float* __restrict__ TO,    // [B, L+1, HS]
    const float* __restrict__ Wd,    // [HS, HD]
    const float* __restrict__ bd,    // [HD]
    const float* __restrict__ Wc,    // [3*HD, C]
    const float* __restrict__ bc,    // [C]
    const int*   __restrict__ wm,    // [B, L]
    const int*   __restrict__ tokl,  // [B]
    const int*   __restrict__ lenp,  // [B]
    unsigned* __restrict__ flags,    // [NBLK]
    float* __restrict__ Wfull,       // [KP, WJ] k-major
    float* __restrict__ AB,          // [NROW, 32]
    float* __restrict__ Tg,          // [NROW, 16]
    float4* __restrict__ out)        // [B*N*N*C/4]
{
    const int blk = blockIdx.x;
    const int t   = threadIdx.x;

    // LDS union (floats):
    //  phase0/1: hsL  = uni[0..3136)       (4 rows x 784)
    //  phase0  : wcT  = uni[3136..7296)    (16 x 260)
    //  phase1  : pLDS = uni[3136..3904)    (16 x 48 partials)
    //  phase2  : sT[0..2560) sB[2560..3840) sA[3840..3968)
    //            sS[3968..6544) pref[6544..6800)
    __shared__ float uni[7296];
    __shared__ int   smap[L];
    __shared__ int   sstart[4], sstop[4];
    __shared__ float sci[4];

    // ---- bar0: self-reset. Stale flag values are only {0xAAAAAAAA, 2, 0};
    // wait until all <= 1 (1 = a fast block already past bar0 -> fine).
    if (t == 0)
        __hip_atomic_store(&flags[blk], 0u, __ATOMIC_RELAXED, __HIP_MEMORY_SCOPE_AGENT);
    if (t < NBLK) {
        int guard = 0;
        while (__hip_atomic_load(&flags[t], __ATOMIC_RELAXED, __HIP_MEMORY_SCOPE_AGENT) > 1u
               && guard < (1 << 22)) {
            __builtin_amdgcn_s_sleep(4);
            ++guard;
        }
    }
    __syncthreads();

    // ======== phase 0 ========
    const int row0 = blk * 4;
    const int b    = row0 / N;            // 4 | 160 -> one batch per block
    const int len  = lenp[b];
    for (int e = t; e < L; e += 256) smap[e] = wm[b * L + e];
    __syncthreads();
    if (t < 4) {
        const int n = (row0 % N) + t;
        int lo = 0, hi = L;
        while (lo < hi) { int m = (lo + hi) >> 1; if (smap[m] < n) lo = m + 1; else hi = m; }
        int lo2 = lo, hi2 = L;
        while (lo2 < hi2) { int m = (lo2 + hi2) >> 1; if (smap[m] < n + 1) lo2 = m + 1; else hi2 = m; }
        const int start = lo < len ? lo : len;
        const int stop  = lo2 < len ? lo2 : len;
        sstart[t] = start; sstop[t] = stop;
        sci[t] = (stop > start) ? 1.0f / (float)(stop - start) : 0.0f;
    }
    __syncthreads();

    float* hsL = uni;                     // [4][KP]
    for (int r = 0; r < 4; ++r) {
        const int start = sstart[r], stop = sstop[r];
        const float ci = sci[r];
        float a0 = 0.f, a1 = 0.f, a2 = 0.f;
        const float* base = TO + ((size_t)b * (L + 1) + 1) * HS;
        for (int l = start; l < stop; ++l) {
            const float* rr = base + (size_t)l * HS;
            a0 += rr[t]; a1 += rr[t + 256]; a2 += rr[t + 512];
        }
        hsL[r * KP + t]       = a0 * ci;
        hsL[r * KP + t + 256] = a1 * ci;
        hsL[r * KP + t + 512] = a2 * ci;
        if (t < 16) hsL[r * KP + 768 + t] = (t == 0 && stop > start) ? 1.0f : 0.0f;
    }

    if (blk < 144) {                      // one Wfull 16-k-stripe x one m-block
        float* wcT = uni + 3136;
        const int kb = blk / 3, m = blk % 3;
        for (int e = t; e < HD * C; e += 256) {
            const int d = e >> 4, c = e & 15;
            wcT[c * WCT_STRIDE + d] = Wc[(size_t)(m * HD + d) * C + c];
        }
        __syncthreads();
        const int kl = t >> 4, c = t & 15;
        const int k = kb * 16 + kl;       // 0..767
        const float4* wd4 = (const float4*)(Wd + (size_t)k * HD);
        const float4* wc4 = (const float4*)(wcT + c * WCT_STRIDE);
        float acc = 0.f;
        #pragma unroll 8
        for (int q = 0; q < HD / 4; ++q) {
            const float4 a = wd4[q];
            const float4 w = wc4[q];
            acc += a.x * w.x + a.y * w.y + a.z * w.z + a.w * w.w;
        }
        Wfull[(size_t)k * WJ + m * 16 + c] = acc;
    } else if (blk == 144) {              // bias row 768 + zero rows 769..783
        if (t < WJ) {
            const int m = t >> 4, c = t & 15;
            float acc = 0.f;
            #pragma unroll 8
            for (int q = 0; q < HD / 4; ++q) {
                const int d = 4 * q;
                const float4 w = *(const float4*)(bd + d);
                acc += w.x * Wc[(size_t)(m * HD + d) * C + c]
                     + w.y * Wc[(size_t)(m * HD + d + 1) * C + c]
                     + w.z * Wc[(size_t)(m * HD + d + 2) * C + c]
                     + w.w * Wc[(size_t)(m * HD + d + 3) * C + c];
            }
            Wfull[(size_t)768 * WJ + t] = acc;
        }
        for (int e = t; e < WJ * 15; e += 256) {
            const int k = 769 + e / WJ, j = e % WJ;
            Wfull[(size_t)k * WJ + j] = 0.f;
        }
    }

    grid_bar(flags, blk, t, 1u);

    // ======== phase 1: gemm for this block's 4 rows ========
    float* pLDS = uni + 3136;             // [16][WJ]
    if (t < 192) {
        const int jq = t % 12, r = (t / 12) % 4, ks = t / 48;   // 4 k-slices
        const float* wf = Wfull + jq * 4;
        float4 acc = {0.f, 0.f, 0.f, 0.f};
        const int kbeg = ks * KSL4;
        #pragma unroll 4
        for (int kk = 0; kk < KSL4; ++kk) {
            const int k = kbeg + kk;
            const float  h = hsL[r * KP + k];                   // LDS broadcast
            const float4 w = *(const float4*)(wf + (size_t)k * WJ); // 192B/wave
            acc.x += h * w.x; acc.y += h * w.y; acc.z += h * w.z; acc.w += h * w.w;
        }
        *(float4*)&pLDS[(ks * 4 + r) * WJ + jq * 4] = acc;
    }
    __syncthreads();
    if (t < 192) {
        const int r = t / WJ, j = t % WJ;
        const float v = pLDS[r * WJ + j] + pLDS[(4 + r) * WJ + j]
                      + pLDS[(8 + r) * WJ + j] + pLDS[(12 + r) * WJ + j];
        const int row = row0 + r;
        const int n = row % N;
        if (j < 32) AB[(size_t)row * 32 + j] = v;
        else        Tg[(size_t)row * 16 + (j - 32)] = (n < tokl[b]) ? v : 0.f;
    }

    grid_bar(flags, blk, t, 2u);

    // ======== phase 2: finalize (it, kh, b2) ========
    const int it = blk % 20;
    const int kh = (blk / 20) % 2;
    const int b2 = blk / 40;
    const int tl = tokl[b2];
    float* sT   = uni;                    // [N*16]
    float* sB   = uni + 2560;             // [KH*16]
    float* sA   = uni + 3840;             // [8*16]
    float* sS   = uni + 3968;             // [(N+1)*16]
    float* pref = uni + 6544;             // [16*16]

    {
        const float4* T4 = (const float4*)(Tg + (size_t)b2 * N * 16);
        float4* sT4 = (float4*)sT;
        for (int e = t; e < N * 4; e += 256) sT4[e] = T4[e];
    }
    for (int e = t; e < KH * 4; e += 256) {
        const int kl = e >> 2, cq = e & 3;
        *(float4*)&sB[kl * 16 + cq * 4] =
            *(const float4*)&AB[((size_t)b2 * N + kh * KH + kl) * 32 + 16 + cq * 4];
    }
    if (t < 32) {
        const int il = t >> 2, cq = t & 3;
        *(float4*)&sA[il * 16 + cq * 4] =
            *(const float4*)&AB[((size_t)b2 * N + it * 8 + il) * 32 + cq * 4];
    }
    if (t < 16) sS[t] = 0.f;
    __syncthreads();

    const int c = t & 15, g = t >> 4;     // 16 chunks of 10
    const int nb = g * 10;
    {
        float run = 0.f;
        for (int u = 0; u < 10; ++u) {
            run += sT[(nb + u) * 16 + c];
            sS[(nb + u + 1) * 16 + c] = run;
        }
        pref[g * 16 + c] = run;
    }
    __syncthreads();
    if (t < 16) {
        float off = 0.f;
        for (int g2 = 0; g2 < 16; ++g2) {
            const float tmp = pref[g2 * 16 + t];
            pref[g2 * 16 + t] = off;
            off += tmp;
        }
    }
    __syncthreads();
    {
        const float off = pref[g * 16 + c];
        for (int u = 0; u < 10; ++u) sS[(nb + u + 1) * 16 + c] += off;
    }
    __syncthreads();

    for (int q = 0; q < 10; ++q) {        // 8 i x 80 k x 4 quads = 2560
        const int qid = t + q * 256;
        const int cq  = qid & 3;
        const int kl  = (qid >> 2) % KH;
        const int il  = (qid >> 2) / KH;
        const int i   = it * 8 + il;
        const int k   = kh * KH + kl;

        float4 v = {0.f, 0.f, 0.f, 0.f};
        if ((i <= k) & (i < tl) & (k < tl)) {
            const float4 a   = *(const float4*)&sA[il * 16 + cq * 4];
            const float4 bb  = *(const float4*)&sB[kl * 16 + cq * 4];
            const float4 sk  = *(const float4*)&sS[(k + 1) * 16 + cq * 4];
            const float4 si  = *(const float4*)&sS[i * 16 + cq * 4];
            const float4 bcq = *(const float4*)&bc[cq * 4];
            const float inv = 1.0f / (float)(k - i + 1);
            v.x = a.x + bb.x + (sk.x - si.x) * inv + bcq.x;
            v.y = a.y + bb.y + (sk.y - si.y) * inv + bcq.y;
            v.z = a.z + bb.z + (sk.z - si.z) * inv + bcq.z;
            v.w = a.w + bb.w + (sk.w - si.w) * inv + bcq.w;
        }
        out[((size_t)(b2 * N + i) * N + k) * 4 + cq] = v;
    }
}

extern "C" void kernel_launch(void* const* d_in, const int* in_sizes, int n_in,
                              void* d_out, int out_size, void* d_ws, size_t ws_size,
                              hipStream_t stream) {
    const float* TO   = (const float*)d_in[0];
    const float* Wd   = (const float*)d_in[1];
    const float* bd   = (const float*)d_in[2];
    const float* Wc   = (const float*)d_in[3];
    const float* bc   = (const float*)d_in[4];
    const int*   wm   = (const int*)d_in[5];
    const int*   tokl = (const int*)d_in[6];
    const int*   lenp = (const int*)d_in[7];

    unsigned* flags = (unsigned*)d_ws;               // [160], bar0 self-resets
    float* base  = (float*)d_ws + 256;               // 1 KB offset, 16B aligned
    float* Wfull = base;                             // 784*48
    float* AB    = Wfull + (size_t)KP * WJ;          // 640*32
    float* Tg    = AB + (size_t)NROW * 32;           // 640*16
    // ~190 KB of ws; everything written before read on every call.

    mega_kernel<<<NBLK, 256, 0, stream>>>(TO, Wd, bd, Wc, bc, wm, tokl, lenp,
                                          flags, Wfull, AB, Tg, (float4*)d_out);
}

// Round 11
// 30.264 us; speedup vs baseline: 1.7440x; 1.7440x over previous
//
#include <hip/hip_runtime.h>

#define B 4
#define L 200
#define N 160
#define HS 768
#define HD 256
#define C 16

#define KP 784             // padded K: 768 data + 1 gate(bias) + 15 zero
#define WJ 48              // fused cols: A(16) | B(16) | T(16)
#define NROW (B * N)       // 640
#define WCT_STRIDE 260     // 65 float4s: odd quad-stride -> conflict-free b128
#define KH 80              // finalize k-half size

// ---------------------------------------------------------------------------
// K1: Wfull build only (145 blocks).
//   blocks 0..143: Wfull[k][m*16+c] = Wd[k,:] . Wc_m[:,c]  (k-major, k<768)
//   block  144   : bias row k=768 (bd . Wc_m) + zero rows 769..783
// ---------------------------------------------------------------------------
__global__ __launch_bounds__(256) void wfull_kernel(
    const float* __restrict__ Wd,      // [HS, HD]
    const float* __restrict__ bd,      // [HD]
    const float* __restrict__ Wc,      // [3*HD, C]
    float* __restrict__ Wfull)         // [KP, WJ]  (k-major)
{
    const int blk = blockIdx.x;
    const int t = threadIdx.x;

    if (blk < 144) {
        const int kb = blk / 3;              // k-stripe 0..47
        const int m  = blk % 3;              // Wc block

        __shared__ float wcT[16 * WCT_STRIDE];   // Wc_m transposed [c][d]
        for (int e = t; e < HD * C; e += 256) {
            const int d = e >> 4, c = e & 15;    // Wc read coalesced (c fast)
            wcT[c * WCT_STRIDE + d] = Wc[(size_t)(m * HD + d) * C + c];
        }
        __syncthreads();

        const int kl = t >> 4, c = t & 15;
        const int k = kb * 16 + kl;              // 0..767 only
        const float4* wd4 = (const float4*)(Wd + (size_t)k * HD);   // L1-bcast x16 c
        const float4* wc4 = (const float4*)(wcT + c * WCT_STRIDE);  // conflict-free
        float acc = 0.f;
        #pragma unroll 8
        for (int q = 0; q < HD / 4; ++q) {
            const float4 a = wd4[q];
            const float4 w = wc4[q];
            acc += a.x * w.x + a.y * w.y + a.z * w.z + a.w * w.w;
        }
        Wfull[(size_t)k * WJ + m * 16 + c] = acc;
    } else {
        if (t < WJ) {
            const int m = t >> 4, c = t & 15;
            float acc = 0.f;
            #pragma unroll 8
            for (int q = 0; q < HD / 4; ++q) {
                const int d = 4 * q;
                const float4 w = *(const float4*)(bd + d);
                acc += w.x * Wc[(size_t)(m * HD + d) * C + c]
                     + w.y * Wc[(size_t)(m * HD + d + 1) * C + c]
                     + w.z * Wc[(size_t)(m * HD + d + 2) * C + c]
                     + w.w * Wc[(size_t)(m * HD + d + 3) * C + c];
            }
            Wfull[(size_t)768 * WJ + t] = acc;
        }
        for (int e = t; e < WJ * 15; e += 256) {
            const int k = 769 + e / WJ, j = e % WJ;
            Wfull[(size_t)k * WJ + j] = 0.f;
        }
    }
}

// ---------------------------------------------------------------------------
// K2: fused pool + GEMM, one (b,n) row per block (640 blocks).
//     Pool the row into LDS (hs never touches global — removes R6-R9's
//     2.5MB write + 2.5MB cross-XCD read), then 48 j x 4 k-slices GEMM:
//     per-k wave-load of Wfull = 48 consecutive floats (R8's proven pattern),
//     hs operand is an LDS same-address broadcast. LDS reduce over slices.
// ---------------------------------------------------------------------------
__global__ __launch_bounds__(256) void poolgemm_kernel(
    const float* __restrict__ TO,      // [B, L+1, HS]
    const float* __restrict__ Wfull,   // [KP, WJ]
    const int*   __restrict__ wm,      // [B, L]
    const int*   __restrict__ lengths, // [B]
    const int*   __restrict__ token_length,
    float* __restrict__ AB,            // [NROW, 32]
    float* __restrict__ Tg)            // [NROW, 16]
{
    const int row = blockIdx.x;
    const int t   = threadIdx.x;
    const int b   = row / N, n = row % N;

    __shared__ int   smap[L];
    __shared__ int   s_start, s_stop;
    __shared__ float s_ci;
    __shared__ float hsL[KP];
    __shared__ float pLDS[4 * WJ];

    for (int e = t; e < L; e += 256) smap[e] = wm[b * L + e];
    __syncthreads();

    if (t == 0) {
        const int len = lengths[b];
        int lo = 0, hi = L;
        while (lo < hi) { int m = (lo + hi) >> 1; if (smap[m] < n) lo = m + 1; else hi = m; }
        int lo2 = lo, hi2 = L;
        while (lo2 < hi2) { int m = (lo2 + hi2) >> 1; if (smap[m] < n + 1) lo2 = m + 1; else hi2 = m; }
        const int start = lo < len ? lo : len;
        const int stop  = lo2 < len ? lo2 : len;
        s_start = start; s_stop = stop;
        s_ci = (stop > start) ? 1.0f / (float)(stop - start) : 0.0f;
    }
    __syncthreads();

    {   // pool: threads own cols t, t+256, t+512
        const int start = s_start, stop = s_stop;
        const float ci = s_ci;
        float a0 = 0.f, a1 = 0.f, a2 = 0.f;
        const float* base = TO + ((size_t)b * (L + 1) + 1) * HS;
        for (int l = start; l < stop; ++l) {
            const float* r = base + (size_t)l * HS;
            a0 += r[t]; a1 += r[t + 256]; a2 += r[t + 512];
        }
        hsL[t]       = a0 * ci;
        hsL[t + 256] = a1 * ci;
        hsL[t + 512] = a2 * ci;
        if (t < 16) hsL[768 + t] = (t == 0 && stop > start) ? 1.0f : 0.0f;
    }
    __syncthreads();

    if (t < 192) {                         // 48 j x 4 k-slices
        const int j  = t % WJ;
        const int ks = t / WJ;
        const int k0 = ks * 196;
        const float* wf = Wfull + j;
        float acc = 0.f;
        #pragma unroll 7
        for (int q = 0; q < 49; ++q) {
            const int k = k0 + 4 * q;
            const float4 h = *(const float4*)&hsL[k];          // LDS broadcast
            acc += h.x * wf[(size_t)k * WJ]       + h.y * wf[(size_t)(k + 1) * WJ]
                 + h.z * wf[(size_t)(k + 2) * WJ] + h.w * wf[(size_t)(k + 3) * WJ];
        }
        pLDS[ks * WJ + j] = acc;
    }
    __syncthreads();

    if (t < WJ) {
        const float v = pLDS[t] + pLDS[WJ + t] + pLDS[2 * WJ + t] + pLDS[3 * WJ + t];
        if (t < 32) AB[(size_t)row * 32 + t] = v;
        else        Tg[(size_t)row * 16 + (t - 32)] = (n < token_length[b]) ? v : 0.f;
    }
}

// ---------------------------------------------------------------------------
// K3: per (b, i-tile of 8, k-half of 80): load AB/T slices, recompute the
//     cheap T->S scan in LDS per block, emit logits with float4 stores.
// ---------------------------------------------------------------------------
__global__ __launch_bounds__(256) void finalize_kernel(
    const float* __restrict__ AB,      // [NROW, 32]
    const float* __restrict__ T,       // [NROW, 16]
    const float* __restrict__ bc,      // [C]
    const int*   __restrict__ token_length,
    float4* __restrict__ out)          // [B*N*N*C/4]
{
    const int it = blockIdx.x;         // 0..19
    const int kh = blockIdx.y;         // 0..1
    const int b  = blockIdx.z;         // 0..3
    const int t  = threadIdx.x;
    const int tl = token_length[b];

    __shared__ float sT[N * 16];       // T cols, all n (scan input)
    __shared__ float sB[KH * 16];      // B cols, this k-half
    __shared__ float sA[8 * 16];       // A cols, this i-tile
    __shared__ float sS[(N + 1) * 16]; // inclusive cumsum, sS[0..15] = 0
    __shared__ float pref[16 * 16];

    {   // T: 2560 contiguous floats -> 640 float4 coalesced
        const float4* T4 = (const float4*)(T + (size_t)b * N * 16);
        float4* sT4 = (float4*)sT;
        for (int e = t; e < N * 4; e += 256) sT4[e] = T4[e];
    }
    for (int e = t; e < KH * 4; e += 256) {      // B cols: 320 float4
        const int kl = e >> 2, cq = e & 3;
        *(float4*)&sB[kl * 16 + cq * 4] =
            *(const float4*)&AB[((size_t)b * N + kh * KH + kl) * 32 + 16 + cq * 4];
    }
    if (t < 32) {                                 // A cols: 32 float4
        const int il = t >> 2, cq = t & 3;
        *(float4*)&sA[il * 16 + cq * 4] =
            *(const float4*)&AB[((size_t)b * N + it * 8 + il) * 32 + cq * 4];
    }
    if (t < 16) sS[t] = 0.f;
    __syncthreads();

    const int c = t & 15, g = t >> 4;            // 16 chunks of 10
    const int nb = g * 10;
    {
        float run = 0.f;
        for (int u = 0; u < 10; ++u) {
            run += sT[(nb + u) * 16 + c];
            sS[(nb + u + 1) * 16 + c] = run;
        }
        pref[g * 16 + c] = run;
    }
    __syncthreads();
    if (t < 16) {
        float off = 0.f;
        for (int g2 = 0; g2 < 16; ++g2) {
            const float tmp = pref[g2 * 16 + t];
            pref[g2 * 16 + t] = off;
            off += tmp;
        }
    }
    __syncthreads();
    {
        const float off = pref[g * 16 + c];
        for (int u = 0; u < 10; ++u) sS[(nb + u + 1) * 16 + c] += off;
    }
    __syncthreads();

    // emit: 8 i x 80 k x 4 c-quads = 2560 quads, 10 per thread
    for (int q = 0; q < 10; ++q) {
        const int qid = t + q * 256;
        const int cq  = qid & 3;
        const int kl  = (qid >> 2) % KH;
        const int il  = (qid >> 2) / KH;
        const int i   = it * 8 + il;
        const int k   = kh * KH + kl;

        float4 v = {0.f, 0.f, 0.f, 0.f};
        if ((i <= k) & (i < tl) & (k < tl)) {
            const float4 a   = *(const float4*)&sA[il * 16 + cq * 4];
            const float4 bb  = *(const float4*)&sB[kl * 16 + cq * 4];
            const float4 sk  = *(const float4*)&sS[(k + 1) * 16 + cq * 4];
            const float4 si  = *(const float4*)&sS[i * 16 + cq * 4];
            const float4 bcq = *(const float4*)&bc[cq * 4];
            const float inv = 1.0f / (float)(k - i + 1);
            v.x = a.x + bb.x + (sk.x - si.x) * inv + bcq.x;
            v.y = a.y + bb.y + (sk.y - si.y) * inv + bcq.y;
            v.z = a.z + bb.z + (sk.z - si.z) * inv + bcq.z;
            v.w = a.w + bb.w + (sk.w - si.w) * inv + bcq.w;
        }
        out[((size_t)(b * N + i) * N + k) * 4 + cq] = v;
    }
}

extern "C" void kernel_launch(void* const* d_in, const int* in_sizes, int n_in,
                              void* d_out, int out_size, void* d_ws, size_t ws_size,
                              hipStream_t stream) {
    const float* TO    = (const float*)d_in[0];
    const float* Wd    = (const float*)d_in[1];
    const float* bd    = (const float*)d_in[2];
    const float* Wc    = (const float*)d_in[3];
    const float* bc    = (const float*)d_in[4];
    const int*   wm    = (const int*)d_in[5];
    const int*   tokl  = (const int*)d_in[6];
    const int*   lenp  = (const int*)d_in[7];

    float* ws    = (float*)d_ws;
    float* Wfull = ws;                               // 784*48
    float* AB    = Wfull + (size_t)KP * WJ;          // 640*32
    float* Tg    = AB + (size_t)NROW * 32;           // 640*16
    // ~270 KB of ws; every element written before read on every call.

    wfull_kernel<<<145, 256, 0, stream>>>(Wd, bd, Wc, Wfull);
    poolgemm_kernel<<<NROW, 256, 0, stream>>>(TO, Wfull, wm, lenp, tokl, AB, Tg);
    finalize_kernel<<<dim3(20, 2, B), 256, 0, stream>>>(AB, Tg, bc, tokl, (float4*)d_out);
}

// Round 13
// 29.503 us; speedup vs baseline: 1.7890x; 1.0258x over previous
//
#include <hip/hip_runtime.h>

#define B 4
#define L 200
#define N 160
#define HS 768
#define HD 256
#define C 16

#define KP 784             // padded K: 768 data + 1 gate(bias) + 15 zero
#define WJ 48              // fused cols: A(16) | B(16) | T(16)
#define NROW (B * N)       // 640
#define WCT_STRIDE 260     // 65 float4s: odd quad-stride -> conflict-free b128
#define KH 40              // finalize k-quarter size

typedef float f4v __attribute__((ext_vector_type(4)));   // native vec for nontemporal

// ---------------------------------------------------------------------------
// K1: Wfull build (145 blocks).
//   blocks 0..143: Wfull[k][m*16+c] = Wd[k,:] . Wc_m[:,c]  (k-major, k<768)
//   block  144   : bias row k=768 (bd . Wc_m) + zero rows 769..783
// ---------------------------------------------------------------------------
__global__ __launch_bounds__(256) void wfull_kernel(
    const float* __restrict__ Wd,      // [HS, HD]
    const float* __restrict__ bd,      // [HD]
    const float* __restrict__ Wc,      // [3*HD, C]
    float* __restrict__ Wfull)         // [KP, WJ]  (k-major)
{
    const int blk = blockIdx.x;
    const int t = threadIdx.x;

    if (blk < 144) {
        const int kb = blk / 3;              // k-stripe 0..47
        const int m  = blk % 3;              // Wc block

        __shared__ float wcT[16 * WCT_STRIDE];   // Wc_m transposed [c][d]
        for (int e = t; e < HD * C; e += 256) {
            const int d = e >> 4, c = e & 15;    // Wc read coalesced (c fast)
            wcT[c * WCT_STRIDE + d] = Wc[(size_t)(m * HD + d) * C + c];
        }
        __syncthreads();

        const int kl = t >> 4, c = t & 15;
        const int k = kb * 16 + kl;              // 0..767 only
        const float4* wd4 = (const float4*)(Wd + (size_t)k * HD);   // L1-bcast x16 c
        const float4* wc4 = (const float4*)(wcT + c * WCT_STRIDE);  // conflict-free
        float acc = 0.f;
        #pragma unroll 8
        for (int q = 0; q < HD / 4; ++q) {
            const float4 a = wd4[q];
            const float4 w = wc4[q];
            acc += a.x * w.x + a.y * w.y + a.z * w.z + a.w * w.w;
        }
        Wfull[(size_t)k * WJ + m * 16 + c] = acc;
    } else {
        if (t < WJ) {
            const int m = t >> 4, c = t & 15;
            float acc = 0.f;
            #pragma unroll 8
            for (int q = 0; q < HD / 4; ++q) {
                const int d = 4 * q;
                const float4 w = *(const float4*)(bd + d);
                acc += w.x * Wc[(size_t)(m * HD + d) * C + c]
                     + w.y * Wc[(size_t)(m * HD + d + 1) * C + c]
                     + w.z * Wc[(size_t)(m * HD + d + 2) * C + c]
                     + w.w * Wc[(size_t)(m * HD + d + 3) * C + c];
            }
            Wfull[(size_t)768 * WJ + t] = acc;
        }
        for (int e = t; e < WJ * 15; e += 256) {
            const int k = 769 + e / WJ, j = e % WJ;
            Wfull[(size_t)k * WJ + j] = 0.f;
        }
    }
}

// ---------------------------------------------------------------------------
// K2: fused pool + GEMM, one (b,n) row per block (640 blocks).
//     Binary search done redundantly by ALL threads (no t==0 serialize);
//     pooling vectorized float4 (192 thr x 1 quad); GEMM 48 j x 4 k-slices
//     with k-major Wfull (48-float coalesced wave-loads, R8 pattern).
// ---------------------------------------------------------------------------
__global__ __launch_bounds__(256) void poolgemm_kernel(
    const float* __restrict__ TO,      // [B, L+1, HS]
    const float* __restrict__ Wfull,   // [KP, WJ]
    const int*   __restrict__ wm,      // [B, L]
    const int*   __restrict__ lengths, // [B]
    const int*   __restrict__ token_length,
    float* __restrict__ AB,            // [NROW, 32]
    float* __restrict__ Tg)            // [NROW, 16]
{
    const int row = blockIdx.x;
    const int t   = threadIdx.x;
    const int b   = row / N, n = row % N;

    __shared__ int   smap[L];
    __shared__ float hsL[KP];
    __shared__ float pLDS[4 * WJ];

    for (int e = t; e < L; e += 256) smap[e] = wm[b * L + e];
    __syncthreads();

    // redundant (wave-uniform) binary search: LDS broadcast reads, no serialize
    const int len = lengths[b];
    int lo = 0, hi = L;
    while (lo < hi) { int m = (lo + hi) >> 1; if (smap[m] < n) lo = m + 1; else hi = m; }
    int lo2 = lo, hi2 = L;
    while (lo2 < hi2) { int m = (lo2 + hi2) >> 1; if (smap[m] < n + 1) lo2 = m + 1; else hi2 = m; }
    const int start = lo < len ? lo : len;
    const int stop  = lo2 < len ? lo2 : len;
    const float ci  = (stop > start) ? 1.0f / (float)(stop - start) : 0.0f;

    if (t < 192) {   // pool: 192 threads x 1 float4 = 768 cols
        float4 a = {0.f, 0.f, 0.f, 0.f};
        const float* base = TO + ((size_t)b * (L + 1) + 1) * HS + 4 * t;
        for (int l = start; l < stop; ++l) {
            const float4 r = *(const float4*)(base + (size_t)l * HS);
            a.x += r.x; a.y += r.y; a.z += r.z; a.w += r.w;
        }
        a.x *= ci; a.y *= ci; a.z *= ci; a.w *= ci;
        *(float4*)&hsL[4 * t] = a;
    } else if (t < 208) {
        hsL[768 + (t - 192)] = (t == 192 && stop > start) ? 1.0f : 0.0f;
    }
    __syncthreads();

    if (t < 192) {                         // 48 j x 4 k-slices
        const int j  = t % WJ;
        const int ks = t / WJ;
        const int k0 = ks * 196;
        const float* wf = Wfull + j;
        float acc = 0.f;
        #pragma unroll 7
        for (int q = 0; q < 49; ++q) {
            const int k = k0 + 4 * q;
            const float4 h = *(const float4*)&hsL[k];          // LDS broadcast
            acc += h.x * wf[(size_t)k * WJ]       + h.y * wf[(size_t)(k + 1) * WJ]
                 + h.z * wf[(size_t)(k + 2) * WJ] + h.w * wf[(size_t)(k + 3) * WJ];
        }
        pLDS[ks * WJ + j] = acc;
    }
    __syncthreads();

    if (t < WJ) {
        const float v = pLDS[t] + pLDS[WJ + t] + pLDS[2 * WJ + t] + pLDS[3 * WJ + t];
        if (t < 32) AB[(size_t)row * 32 + t] = v;
        else        Tg[(size_t)row * 16 + (t - 32)] = (n < token_length[b]) ? v : 0.f;
    }
}

// ---------------------------------------------------------------------------
// K3: per (b, i-tile of 8, k-quarter of 40): load AB/T slices, recompute the
//     cheap T->S scan in LDS, emit logits via nontemporal float4 stores.
//     320 blocks (2x R11's TLP for latency hiding).
// ---------------------------------------------------------------------------
__global__ __launch_bounds__(256) void finalize_kernel(
    const float* __restrict__ AB,      // [NROW, 32]
    const float* __restrict__ T,       // [NROW, 16]
    const float* __restrict__ bc,      // [C]
    const int*   __restrict__ token_length,
    f4v* __restrict__ out)             // [B*N*N*C/4]
{
    const int it = blockIdx.x;         // 0..19
    const int kh = blockIdx.y;         // 0..3
    const int b  = blockIdx.z;         // 0..3
    const int t  = threadIdx.x;
    const int tl = token_length[b];

    __shared__ float sT[N * 16];       // T cols, all n (scan input)
    __shared__ float sB[KH * 16];      // B cols, this k-quarter
    __shared__ float sA[8 * 16];       // A cols, this i-tile
    __shared__ float sS[(N + 1) * 16]; // inclusive cumsum, sS[0..15] = 0
    __shared__ float pref[16 * 16];

    {   // T: 2560 contiguous floats -> 640 float4 coalesced
        const float4* T4 = (const float4*)(T + (size_t)b * N * 16);
        float4* sT4 = (float4*)sT;
        for (int e = t; e < N * 4; e += 256) sT4[e] = T4[e];
    }
    if (t < KH * 4) {                             // B cols: 160 float4
        const int kl = t >> 2, cq = t & 3;
        *(float4*)&sB[kl * 16 + cq * 4] =
            *(const float4*)&AB[((size_t)b * N + kh * KH + kl) * 32 + 16 + cq * 4];
    }
    if (t >= 192 && t < 224) {                    // A cols: 32 float4
        const int il = (t - 192) >> 2, cq = t & 3;
        *(float4*)&sA[il * 16 + cq * 4] =
            *(const float4*)&AB[((size_t)b * N + it * 8 + il) * 32 + cq * 4];
    }
    if (t >= 224 && t < 240) sS[t - 224] = 0.f;
    __syncthreads();

    const int c = t & 15, g = t >> 4;            // 16 chunks of 10
    const int nb = g * 10;
    {
        float run = 0.f;
        for (int u = 0; u < 10; ++u) {
            run += sT[(nb + u) * 16 + c];
            sS[(nb + u + 1) * 16 + c] = run;
        }
        pref[g * 16 + c] = run;
    }
    __syncthreads();
    if (t < 16) {
        float off = 0.f;
        for (int g2 = 0; g2 < 16; ++g2) {
            const float tmp = pref[g2 * 16 + t];
            pref[g2 * 16 + t] = off;
            off += tmp;
        }
    }
    __syncthreads();
    {
        const float off = pref[g * 16 + c];
        for (int u = 0; u < 10; ++u) sS[(nb + u + 1) * 16 + c] += off;
    }
    __syncthreads();

    // emit: 8 i x 40 k x 4 c-quads = 1280 quads, 5 per thread
    for (int q = 0; q < 5; ++q) {
        const int qid = t + q * 256;
        const int cq  = qid & 3;
        const int kl  = (qid >> 2) % KH;
        const int il  = (qid >> 2) / KH;
        const int i   = it * 8 + il;
        const int k   = kh * KH + kl;

        f4v v = {0.f, 0.f, 0.f, 0.f};
        if ((i <= k) & (i < tl) & (k < tl)) {
            const float4 a   = *(const float4*)&sA[il * 16 + cq * 4];
            const float4 bb  = *(const float4*)&sB[kl * 16 + cq * 4];
            const float4 sk  = *(const float4*)&sS[(k + 1) * 16 + cq * 4];
            const float4 si  = *(const float4*)&sS[i * 16 + cq * 4];
            const float4 bcq = *(const float4*)&bc[cq * 4];
            const float inv = 1.0f / (float)(k - i + 1);
            v.x = a.x + bb.x + (sk.x - si.x) * inv + bcq.x;
            v.y = a.y + bb.y + (sk.y - si.y) * inv + bcq.y;
            v.z = a.z + bb.z + (sk.z - si.z) * inv + bcq.z;
            v.w = a.w + bb.w + (sk.w - si.w) * inv + bcq.w;
        }
        __builtin_nontemporal_store(v, &out[((size_t)(b * N + i) * N + k) * 4 + cq]);
    }
}

extern "C" void kernel_launch(void* const* d_in, const int* in_sizes, int n_in,
                              void* d_out, int out_size, void* d_ws, size_t ws_size,
                              hipStream_t stream) {
    const float* TO    = (const float*)d_in[0];
    const float* Wd    = (const float*)d_in[1];
    const float* bd    = (const float*)d_in[2];
    const float* Wc    = (const float*)d_in[3];
    const float* bc    = (const float*)d_in[4];
    const int*   wm    = (const int*)d_in[5];
    const int*   tokl  = (const int*)d_in[6];
    const int*   lenp  = (const int*)d_in[7];

    float* ws    = (float*)d_ws;
    float* Wfull = ws;                               // 784*48
    float* AB    = Wfull + (size_t)KP * WJ;          // 640*32
    float* Tg    = AB + (size_t)NROW * 32;           // 640*16
    // ~270 KB of ws; every element written before read on every call.

    wfull_kernel<<<145, 256, 0, stream>>>(Wd, bd, Wc, Wfull);
    poolgemm_kernel<<<NROW, 256, 0, stream>>>(TO, Wfull, wm, lenp, tokl, AB, Tg);
    finalize_kernel<<<dim3(20, 4, B), 256, 0, stream>>>(AB, Tg, bc, tokl, (f4v*)d_out);
}